// Round 6
// baseline (446.162 us; speedup 1.0000x reference)
//
#include <hip/hip_runtime.h>
#include <hip/hip_bf16.h>
#include <cstdint>
#include <cstddef>

typedef __bf16 bf16;
typedef __bf16 bf16x4 __attribute__((ext_vector_type(4)));
typedef __bf16 bf16x8 __attribute__((ext_vector_type(8)));
typedef float f32x4 __attribute__((ext_vector_type(4)));
typedef float f32x16 __attribute__((ext_vector_type(16)));

#define MFMA16(a, b, c) __builtin_amdgcn_mfma_f32_16x16x32_bf16((a), (b), (c), 0, 0, 0)
#define MFMA32(a, b, c) __builtin_amdgcn_mfma_f32_32x32x16_bf16((a), (b), (c), 0, 0, 0)
#define GLD16(g, l) __builtin_amdgcn_global_load_lds( \
    (const __attribute__((address_space(1))) void*)(g), \
    (__attribute__((address_space(3))) void*)(l), 16, 0, 0)

constexpr int Bsz = 4, SX = 2048, SC = 2048, Dm = 512, H = 8, DK = 64;
constexpr float L2E = 1.4426950408889634f;

// ---------------------------------------------------------------------------
// cvt kernels
// ---------------------------------------------------------------------------
__global__ __launch_bounds__(256) void cvt_weights(
    const float* __restrict__ Wq, const float* __restrict__ Wk,
    const float* __restrict__ Wv, const float* __restrict__ Wo,
    bf16* __restrict__ out)
{
    int i = (blockIdx.x * 256 + threadIdx.x) * 8;
    int w = i >> 18;
    int off = i & 262143;
    const float* src = (w == 0) ? Wq : (w == 1) ? Wk : (w == 2) ? Wv : Wo;
    float4 v0 = *(const float4*)(src + off);
    float4 v1 = *(const float4*)(src + off + 4);
    bf16x8 o = { (bf16)v0.x, (bf16)v0.y, (bf16)v0.z, (bf16)v0.w,
                 (bf16)v1.x, (bf16)v1.y, (bf16)v1.z, (bf16)v1.w };
    *(bf16x8*)(out + i) = o;
}

__global__ __launch_bounds__(256) void cvt_xc(
    const float* __restrict__ x, const float* __restrict__ c,
    bf16* __restrict__ out)
{
    int i = (blockIdx.x * 256 + threadIdx.x) * 8;
    const float* src = (i < 4194304) ? x : c;
    int off = i & 4194303;
    float4 v0 = *(const float4*)(src + off);
    float4 v1 = *(const float4*)(src + off + 4);
    bf16x8 o = { (bf16)v0.x, (bf16)v0.y, (bf16)v0.z, (bf16)v0.w,
                 (bf16)v1.x, (bf16)v1.y, (bf16)v1.z, (bf16)v1.w };
    *(bf16x8*)(out + i) = o;
}

// rel_table (4095 x 8) -> relT (8 x 4095), pre-scaled by log2(e)
__global__ __launch_bounds__(256) void cvt_rel(
    const float* __restrict__ rel, float* __restrict__ relT)
{
    int h = blockIdx.y;
    int i = blockIdx.x * 256 + threadIdx.x;
    if (i < SX + SC - 1) relT[h * (SX + SC - 1) + i] = rel[i * H + h] * L2E;
}

// ---------------------------------------------------------------------------
// proj_gemm: Y = A @ W^T + bias.  A bf16 (M x 512), W bf16 (N x 512).
// Tile 128(M) x 64(N), BK=64, 256 thr = 4 waves, wave tile 64x32 (4x2 MFMA16).
// global_load_lds staging with PER-WAVE LDS bases, XOR chunk swizzle.
// MODE 0: Y bf16 std [(bh)*2048 + s]*64 + dk                          (Q)
// MODE 3: Y bf16 K-frag ((((bh*64+key/32)*4+ks)*2+l5)*32+key%32)*8+j  (K)
// MODE 4: Y bf16 V-frag (((((bh*32+key/64)*4+ks)*2+ng)*2+l5)*32+dk%32)*8+j
// MODE 2: Y fp32 m*512 + n                                            (out)
// ---------------------------------------------------------------------------
template <int MODE>
__global__ __launch_bounds__(256, 2) void proj_gemm(
    const bf16* __restrict__ A, const bf16* __restrict__ W,
    const float* __restrict__ bias, void* __restrict__ Yv)
{
    __shared__ alignas(16) bf16 As[128 * 64];
    __shared__ alignas(16) bf16 Bs[64 * 64];

    const int t = threadIdx.x;
    const int n0 = blockIdx.x * 64;
    const int m0 = blockIdx.y * 128;
    const int wid = t >> 6, lane = t & 63, lr = lane & 15, lq = lane >> 4;
    const int wm = (wid & 1) * 64, wn = (wid >> 1) * 32;

    const int rl = lane >> 3;             // 0..7 row within 8-row staging group
    const int ch = (lane & 7) ^ rl;       // xor-swizzled global 16B chunk

    f32x4 acc[4][2];
#pragma unroll
    for (int i = 0; i < 4; i++)
#pragma unroll
        for (int j = 0; j < 2; j++) acc[i][j] = f32x4{0.f, 0.f, 0.f, 0.f};

    for (int k0 = 0; k0 < Dm; k0 += 64) {
        const bf16* ga = A + (size_t)(m0 + wid * 32 + rl) * Dm + k0 + ch * 8;
        const bf16* gb = W + (size_t)(n0 + wid * 16 + rl) * Dm + k0 + ch * 8;
#pragma unroll
        for (int g = 0; g < 4; g++)
            GLD16(ga + (size_t)g * 8 * Dm, &As[(wid * 32 + g * 8) * 64]);
#pragma unroll
        for (int g = 0; g < 2; g++)
            GLD16(gb + (size_t)g * 8 * Dm, &Bs[(wid * 16 + g * 8) * 64]);
        __syncthreads();
#pragma unroll
        for (int ks = 0; ks < 2; ks++) {
            bf16x8 af[4], bfr[2];
#pragma unroll
            for (int mt = 0; mt < 4; mt++)
                af[mt] = *(const bf16x8*)&As[(wm + mt * 16 + lr) * 64 + (((ks * 4 + lq) ^ (lr & 7)) * 8)];
#pragma unroll
            for (int nt = 0; nt < 2; nt++)
                bfr[nt] = *(const bf16x8*)&Bs[(wn + nt * 16 + lr) * 64 + (((ks * 4 + lq) ^ (lr & 7)) * 8)];
#pragma unroll
            for (int mt = 0; mt < 4; mt++)
#pragma unroll
                for (int nt = 0; nt < 2; nt++)
                    acc[mt][nt] = MFMA16(af[mt], bfr[nt], acc[mt][nt]);
        }
        __syncthreads();
    }

    // epilogue
#pragma unroll
    for (int mt = 0; mt < 4; mt++) {
#pragma unroll
        for (int nt = 0; nt < 2; nt++) {
#pragma unroll
            for (int r = 0; r < 4; r++) {
                int m = m0 + wm + mt * 16 + lq * 4 + r;   // b*2048 + s
                int n = n0 + wn + nt * 16 + lr;           // h*64 + dk
                float v = acc[mt][nt][r] + bias[n];
                int bh = (m >> 11) * 8 + (n >> 6);
                int key = m & 2047, dk = n & 63;
                if constexpr (MODE == 0) {
                    ((bf16*)Yv)[(size_t)(bh * 2048 + key) * 64 + dk] = (bf16)v;
                } else if constexpr (MODE == 3) {
                    int idx = ((((bh * 64 + (key >> 5)) * 4 + (dk >> 4)) * 2 + ((dk >> 3) & 1)) * 32
                               + (key & 31)) * 8 + (dk & 7);
                    ((bf16*)Yv)[idx] = (bf16)v;
                } else if constexpr (MODE == 4) {
                    int idx = (((((bh * 32 + (key >> 6)) * 4 + ((key >> 4) & 3)) * 2 + (dk >> 5)) * 2
                                + ((key >> 3) & 1)) * 32 + (dk & 31)) * 8 + (key & 7);
                    ((bf16*)Yv)[idx] = (bf16)v;
                } else {
                    ((float*)Yv)[(size_t)m * Dm + n] = v;
                }
            }
        }
    }
}

// ---------------------------------------------------------------------------
// attn v6 = R3 shape (2048 blocks x 128 thr, proven XCD/L2 locality) +
// fragment-major K/V (coalesced 1KB wave-loads) + register-rotate pipelining:
// consume kcur in S-MFMAs then immediately reload it with tile t+1's K;
// consume vcur in PV then reload with t+1's V. Latency hides behind a full
// tile phase. Wave w owns keys [w*1024, +1024), 16 tiles; barrier-free loop.
// ---------------------------------------------------------------------------
constexpr int PST = 72;  // P row stride (bf16)

__global__ __launch_bounds__(128, 4) void attn_kernel(
    const bf16* __restrict__ Qm, const bf16* __restrict__ Kf,
    const bf16* __restrict__ Vf, const float* __restrict__ relT,
    bf16* __restrict__ Oa)
{
    const int id = blockIdx.x;
    const int xcd = id & 7, j = id >> 3;
    const int bh = xcd + 8 * (j & 3);
    const int q0 = (j >> 2) * 32;
    const int h = bh & 7, b = bh >> 3;
    const int t = threadIdx.x;
    const int wid = t >> 6, lane = t & 63;
    const int l31 = lane & 31, l5 = lane >> 5;

    __shared__ alignas(16) char sm[19456];
    bf16*  Ps   = (bf16*)(sm + wid * 4608);      // per-wave 32 x PST
    float* Osum = (float*)(sm + 9216);           // 64 lanes x 36 floats
    float* Bsl  = (float*)(sm + 18432) + wid * 96;
    float* Ls1  = (float*)(sm + 19200);
    float* Lfin = (float*)(sm + 19328);

    const bf16* Qb = Qm + (size_t)bh * SC * DK;
    const bf16* Kb = Kf + (size_t)bh * 64 * 2048;   // 64 key-grps x (4 ks x 512)
    const bf16* Vb = Vf + (size_t)bh * 32 * 4096;   // 32 tiles x (4 ks x 2 ng x 512)
    const float* rT = relT + h * (SX + SC - 1);

    // Q B-fragments (n=q, k=dk), resident all kernel
    bf16x8 qf[4];
#pragma unroll
    for (int ks = 0; ks < 4; ks++)
        qf[ks] = *(const bf16x8*)&Qb[(size_t)(q0 + l31) * DK + ks * 16 + l5 * 8];

    f32x16 oacc[2];
#pragma unroll
    for (int ng = 0; ng < 2; ng++)
#pragma unroll
        for (int r = 0; r < 16; r++) oacc[ng][r] = 0.f;
    float lsum = 0.f;

    const float sc = 0.125f * L2E;
    const int kw0 = wid << 10;       // wave's key base
    const int tile0 = wid << 4;      // wave's first 64-key tile (of 32 per bh)

    // ---- prologue: load tile 0's K and V into registers ----
    bf16x8 kcur[8], vcur[8];
    {
        const bf16* kb = Kb + (size_t)(tile0 * 2) * 2048 + lane * 8;
#pragma unroll
        for (int kg = 0; kg < 2; kg++)
#pragma unroll
            for (int ks = 0; ks < 4; ks++)
                kcur[kg * 4 + ks] = *(const bf16x8*)(kb + kg * 2048 + ks * 512);
        const bf16* vb = Vb + (size_t)tile0 * 4096 + lane * 8;
#pragma unroll
        for (int ng = 0; ng < 2; ng++)
#pragma unroll
            for (int ks = 0; ks < 4; ks++)
                vcur[ng * 4 + ks] = *(const bf16x8*)(vb + ng * 512 + ks * 1024);
    }

#pragma unroll 1
    for (int tt = 0; tt < 16; ++tt) {
        const int k0 = kw0 + tt * 64;
        int i0 = q0 - k0 + 1984;
        Bsl[lane] = rT[i0 + lane];
        if (lane < 31) Bsl[64 + lane] = rT[i0 + 64 + lane];

        const int ntile = tile0 + tt + 1;
        // ---- S^T = K·Q^T per 32-key group; rotate-reload kcur; exp2; P->LDS
#pragma unroll
        for (int kg = 0; kg < 2; kg++) {
            f32x16 s;
#pragma unroll
            for (int r = 0; r < 16; r++) s[r] = 0.f;
#pragma unroll
            for (int ks = 0; ks < 4; ks++)
                s = MFMA32(kcur[kg * 4 + ks], qf[ks], s);  // D[key][q], col=q
            if (tt < 15) {
                const bf16* kb = Kb + (size_t)(ntile * 2 + kg) * 2048 + lane * 8;
#pragma unroll
                for (int ks = 0; ks < 4; ks++)
                    kcur[kg * 4 + ks] = *(const bf16x8*)(kb + ks * 512);
            }
#pragma unroll
            for (int r4 = 0; r4 < 4; r4++) {
                float p[4];
#pragma unroll
                for (int r0 = 0; r0 < 4; r0++) {
                    int n = r0 + 8 * r4 + 4 * l5;            // key_local in group
                    int ib = 63 + l31 - (kg * 32 + n);
                    p[r0] = __builtin_amdgcn_exp2f(s[r4 * 4 + r0] * sc + Bsl[ib]);
                    lsum += p[r0];
                }
                bf16x4 pk = { (bf16)p[0], (bf16)p[1], (bf16)p[2], (bf16)p[3] };
                *(bf16x4*)&Ps[l31 * PST + kg * 32 + 8 * r4 + 4 * l5] = pk;
            }
        }
        // ---- O += P @ V ; rotate-reload vcur ----
        bf16x8 pf[4];
#pragma unroll
        for (int ks = 0; ks < 4; ks++)
            pf[ks] = *(const bf16x8*)&Ps[l31 * PST + ks * 16 + l5 * 8];
#pragma unroll
        for (int ng = 0; ng < 2; ng++) {
#pragma unroll
            for (int ks = 0; ks < 4; ks++)
                oacc[ng] = MFMA32(pf[ks], vcur[ng * 4 + ks], oacc[ng]);  // D[q][dk]
            if (tt < 15) {
                const bf16* vb = Vb + (size_t)ntile * 4096 + ng * 512 + lane * 8;
#pragma unroll
                for (int ks = 0; ks < 4; ks++)
                    vcur[ng * 4 + ks] = *(const bf16x8*)(vb + ks * 1024);
            }
        }
    }

    // ---- 2-way combine (R3) ----
    lsum += __shfl_xor(lsum, 32, 64);
    if (wid == 1) {
        if (lane < 32) Ls1[l31] = lsum;
        float* Op = Osum + lane * 36;
#pragma unroll
        for (int ng = 0; ng < 2; ng++)
#pragma unroll
            for (int q = 0; q < 4; q++) {
                f32x4 v = { oacc[ng][q * 4 + 0], oacc[ng][q * 4 + 1],
                            oacc[ng][q * 4 + 2], oacc[ng][q * 4 + 3] };
                *(f32x4*)(Op + ng * 16 + q * 4) = v;
            }
    }
    __syncthreads();
    if (wid == 0) {
        lsum += Ls1[l31];
        const float* Op = Osum + lane * 36;
#pragma unroll
        for (int ng = 0; ng < 2; ng++)
#pragma unroll
            for (int q = 0; q < 4; q++) {
                f32x4 v = *(const f32x4*)(Op + ng * 16 + q * 4);
#pragma unroll
                for (int r0 = 0; r0 < 4; r0++) oacc[ng][q * 4 + r0] += v[r0];
            }
        if (lane < 32) Lfin[l31] = lsum;
        // epilogue: normalize, store bf16 [b][q][h*64+dk]
#pragma unroll
        for (int r4 = 0; r4 < 4; r4++) {
            float4 lv = *(const float4*)&Lfin[8 * r4 + 4 * l5];
            float rv[4] = { 1.f / lv.x, 1.f / lv.y, 1.f / lv.z, 1.f / lv.w };
#pragma unroll
            for (int ng = 0; ng < 2; ng++) {
#pragma unroll
                for (int r0 = 0; r0 < 4; r0++) {
                    int row = r0 + 8 * r4 + 4 * l5;
                    Oa[((size_t)(b * SX + q0 + row)) * Dm + h * 64 + ng * 32 + l31] =
                        (bf16)(oacc[ng][r4 * 4 + r0] * rv[r0]);
                }
            }
        }
    }
}

// ---------------------------------------------------------------------------
// Launch
// ---------------------------------------------------------------------------
extern "C" void kernel_launch(void* const* d_in, const int* in_sizes, int n_in,
                              void* d_out, int out_size, void* d_ws, size_t ws_size,
                              hipStream_t stream)
{
    (void)in_sizes; (void)n_in; (void)out_size; (void)ws_size;

    const float* x   = (const float*)d_in[0];
    const float* c   = (const float*)d_in[1];
    const float* Wq  = (const float*)d_in[2];
    const float* bq  = (const float*)d_in[3];
    const float* Wk  = (const float*)d_in[4];
    const float* bk  = (const float*)d_in[5];
    const float* Wv  = (const float*)d_in[6];
    const float* bv  = (const float*)d_in[7];
    const float* Wo  = (const float*)d_in[8];
    const float* bo  = (const float*)d_in[9];
    const float* rel = (const float*)d_in[10];

    char* ws = (char*)d_ws;
    // layout: Wbf 0..2MB | XCbf 2..18MB (dead after V) / Aw overlay 2..10MB
    //         Q 18..26 | Kf 26..34 | Vf 34..42 | relT 42MB+128KB
    bf16*  Wbf  = (bf16*)ws;
    bf16*  Xbf  = (bf16*)(ws + (2u << 20));
    bf16*  Cbf  = Xbf + 4194304;
    bf16*  Aw   = (bf16*)(ws + (2u << 20));      // overlays XCbf (dead by then)
    bf16*  Qw   = (bf16*)(ws + (18u << 20));
    bf16*  Kw   = (bf16*)(ws + (26u << 20));
    bf16*  Vw   = (bf16*)(ws + (34u << 20));
    float* relT = (float*)(ws + (42u << 20));

    cvt_weights<<<512, 256, 0, stream>>>(Wq, Wk, Wv, Wo, Wbf);
    cvt_xc<<<4096, 256, 0, stream>>>(x, c, Xbf);
    cvt_rel<<<dim3(16, 8), 256, 0, stream>>>(rel, relT);

    dim3 pg(8, 64);  // (N/64, M/128)
    proj_gemm<0><<<pg, 256, 0, stream>>>(Xbf, Wbf + 0 * 262144, bq, Qw);
    proj_gemm<3><<<pg, 256, 0, stream>>>(Cbf, Wbf + 1 * 262144, bk, Kw);
    proj_gemm<4><<<pg, 256, 0, stream>>>(Cbf, Wbf + 2 * 262144, bv, Vw);

    attn_kernel<<<2048, 128, 0, stream>>>(Qw, Kw, Vw, relT, Aw);

    proj_gemm<2><<<pg, 256, 0, stream>>>(Aw, Wbf + 3 * 262144, bo, d_out);
}

// Round 7
// 218.984 us; speedup vs baseline: 2.0374x; 2.0374x over previous
//
#include <hip/hip_runtime.h>
#include <hip/hip_bf16.h>
#include <cstdint>
#include <cstddef>

typedef __bf16 bf16;
typedef __bf16 bf16x4 __attribute__((ext_vector_type(4)));
typedef __bf16 bf16x8 __attribute__((ext_vector_type(8)));
typedef float f32x4 __attribute__((ext_vector_type(4)));
typedef float f32x16 __attribute__((ext_vector_type(16)));

#define MFMA16(a, b, c) __builtin_amdgcn_mfma_f32_16x16x32_bf16((a), (b), (c), 0, 0, 0)
#define MFMA32(a, b, c) __builtin_amdgcn_mfma_f32_32x32x16_bf16((a), (b), (c), 0, 0, 0)
#define GLD16(g, l) __builtin_amdgcn_global_load_lds( \
    (const __attribute__((address_space(1))) void*)(g), \
    (__attribute__((address_space(3))) void*)(l), 16, 0, 0)

constexpr int Bsz = 4, SX = 2048, SC = 2048, Dm = 512, H = 8, DK = 64;
constexpr float L2E = 1.4426950408889634f;

// ---------------------------------------------------------------------------
// cvt kernels
// ---------------------------------------------------------------------------
__global__ __launch_bounds__(256) void cvt_weights(
    const float* __restrict__ Wq, const float* __restrict__ Wk,
    const float* __restrict__ Wv, const float* __restrict__ Wo,
    bf16* __restrict__ out)
{
    int i = (blockIdx.x * 256 + threadIdx.x) * 8;
    int w = i >> 18;
    int off = i & 262143;
    const float* src = (w == 0) ? Wq : (w == 1) ? Wk : (w == 2) ? Wv : Wo;
    float4 v0 = *(const float4*)(src + off);
    float4 v1 = *(const float4*)(src + off + 4);
    bf16x8 o = { (bf16)v0.x, (bf16)v0.y, (bf16)v0.z, (bf16)v0.w,
                 (bf16)v1.x, (bf16)v1.y, (bf16)v1.z, (bf16)v1.w };
    *(bf16x8*)(out + i) = o;
}

__global__ __launch_bounds__(256) void cvt_xc(
    const float* __restrict__ x, const float* __restrict__ c,
    bf16* __restrict__ out)
{
    int i = (blockIdx.x * 256 + threadIdx.x) * 8;
    const float* src = (i < 4194304) ? x : c;
    int off = i & 4194303;
    float4 v0 = *(const float4*)(src + off);
    float4 v1 = *(const float4*)(src + off + 4);
    bf16x8 o = { (bf16)v0.x, (bf16)v0.y, (bf16)v0.z, (bf16)v0.w,
                 (bf16)v1.x, (bf16)v1.y, (bf16)v1.z, (bf16)v1.w };
    *(bf16x8*)(out + i) = o;
}

// rel_table (4095 x 8) -> relT (8 x 4095), pre-scaled by log2(e)
__global__ __launch_bounds__(256) void cvt_rel(
    const float* __restrict__ rel, float* __restrict__ relT)
{
    int h = blockIdx.y;
    int i = blockIdx.x * 256 + threadIdx.x;
    if (i < SX + SC - 1) relT[h * (SX + SC - 1) + i] = rel[i * H + h] * L2E;
}

// ---------------------------------------------------------------------------
// proj_gemm v3: Y = A @ W^T + bias.  A bf16 (M x 512), W bf16 (N x 512).
// Tile 128(M) x 128(N), BK=64, 256 thr = 4 waves, wave tile 64x64 (4x4 MFMA16).
// FLOP per LDS-byte = 32 (vs 21.3 at 64x32 wave tile) — GEMM is LDS-pipe-bound.
// global_load_lds staging with PER-WAVE LDS bases, XOR chunk swizzle.
// MODE 0: Y bf16 std [(bh)*2048 + s]*64 + dk                          (Q)
// MODE 3: Y bf16 K-frag ((((bh*64+key/32)*4+ks)*2+l5)*32+key%32)*8+j  (K)
// MODE 4: Y bf16 V-frag (((((bh*32+key/64)*4+ks)*2+ng)*2+l5)*32+dk%32)*8+j
// MODE 2: Y fp32 m*512 + n                                            (out)
// ---------------------------------------------------------------------------
template <int MODE>
__global__ __launch_bounds__(256, 2) void proj_gemm(
    const bf16* __restrict__ A, const bf16* __restrict__ W,
    const float* __restrict__ bias, void* __restrict__ Yv)
{
    __shared__ alignas(16) bf16 As[128 * 64];
    __shared__ alignas(16) bf16 Bs[128 * 64];

    const int t = threadIdx.x;
    const int n0 = blockIdx.x * 128;
    const int m0 = blockIdx.y * 128;
    const int wid = t >> 6, lane = t & 63, lr = lane & 15, lq = lane >> 4;
    const int wm = (wid & 1) * 64, wn = (wid >> 1) * 64;

    const int rl = lane >> 3;             // 0..7 row within 8-row staging group
    const int ch = (lane & 7) ^ rl;       // xor-swizzled global 16B chunk

    f32x4 acc[4][4];
#pragma unroll
    for (int i = 0; i < 4; i++)
#pragma unroll
        for (int j = 0; j < 4; j++) acc[i][j] = f32x4{0.f, 0.f, 0.f, 0.f};

    for (int k0 = 0; k0 < Dm; k0 += 64) {
        // wave `wid` stages A-rows and B-rows [wid*32, wid*32+32)
        const bf16* ga = A + (size_t)(m0 + wid * 32 + rl) * Dm + k0 + ch * 8;
        const bf16* gb = W + (size_t)(n0 + wid * 32 + rl) * Dm + k0 + ch * 8;
#pragma unroll
        for (int g = 0; g < 4; g++)
            GLD16(ga + (size_t)g * 8 * Dm, &As[(wid * 32 + g * 8) * 64]);
#pragma unroll
        for (int g = 0; g < 4; g++)
            GLD16(gb + (size_t)g * 8 * Dm, &Bs[(wid * 32 + g * 8) * 64]);
        __syncthreads();
#pragma unroll
        for (int ks = 0; ks < 2; ks++) {
            bf16x8 af[4], bfr[4];
#pragma unroll
            for (int mt = 0; mt < 4; mt++)
                af[mt] = *(const bf16x8*)&As[(wm + mt * 16 + lr) * 64 + (((ks * 4 + lq) ^ (lr & 7)) * 8)];
#pragma unroll
            for (int nt = 0; nt < 4; nt++)
                bfr[nt] = *(const bf16x8*)&Bs[(wn + nt * 16 + lr) * 64 + (((ks * 4 + lq) ^ (lr & 7)) * 8)];
#pragma unroll
            for (int mt = 0; mt < 4; mt++)
#pragma unroll
                for (int nt = 0; nt < 4; nt++)
                    acc[mt][nt] = MFMA16(af[mt], bfr[nt], acc[mt][nt]);
        }
        __syncthreads();
    }

    // epilogue
#pragma unroll
    for (int mt = 0; mt < 4; mt++) {
#pragma unroll
        for (int nt = 0; nt < 4; nt++) {
#pragma unroll
            for (int r = 0; r < 4; r++) {
                int m = m0 + wm + mt * 16 + lq * 4 + r;   // b*2048 + s
                int n = n0 + wn + nt * 16 + lr;           // h*64 + dk
                float v = acc[mt][nt][r] + bias[n];
                int bh = (m >> 11) * 8 + (n >> 6);
                int key = m & 2047, dk = n & 63;
                if constexpr (MODE == 0) {
                    ((bf16*)Yv)[(size_t)(bh * 2048 + key) * 64 + dk] = (bf16)v;
                } else if constexpr (MODE == 3) {
                    int idx = ((((bh * 64 + (key >> 5)) * 4 + (dk >> 4)) * 2 + ((dk >> 3) & 1)) * 32
                               + (key & 31)) * 8 + (dk & 7);
                    ((bf16*)Yv)[idx] = (bf16)v;
                } else if constexpr (MODE == 4) {
                    int idx = (((((bh * 32 + (key >> 6)) * 4 + ((key >> 4) & 3)) * 2 + (dk >> 5)) * 2
                                + ((key >> 3) & 1)) * 32 + (dk & 31)) * 8 + (key & 7);
                    ((bf16*)Yv)[idx] = (bf16)v;
                } else {
                    ((float*)Yv)[(size_t)m * Dm + n] = v;
                }
            }
        }
    }
}

// ---------------------------------------------------------------------------
// attn v7 = R3 structure EXACTLY (2048 blocks x 128 thr, proven FETCH=12 MB,
// VGPR~60) with ONLY the K/V load addresses changed to fragment-major layout:
// every kf/vf fetch is one contiguous 1 KB wave-load (base + lane*16B).
// No register prefetch (R6's rotate spilled to scratch).
// Wave w owns keys [w*1024, +1024), 16 tiles; barrier-free K-loop.
// ---------------------------------------------------------------------------
constexpr int PST = 72;  // P row stride (bf16)

__global__ __launch_bounds__(128, 4) void attn_kernel(
    const bf16* __restrict__ Qm, const bf16* __restrict__ Kf,
    const bf16* __restrict__ Vf, const float* __restrict__ relT,
    bf16* __restrict__ Oa)
{
    const int id = blockIdx.x;
    const int xcd = id & 7, j = id >> 3;
    const int bh = xcd + 8 * (j & 3);
    const int q0 = (j >> 2) * 32;
    const int h = bh & 7, b = bh >> 3;
    const int t = threadIdx.x;
    const int wid = t >> 6, lane = t & 63;
    const int l31 = lane & 31, l5 = lane >> 5;

    __shared__ alignas(16) char sm[19456];
    bf16*  Ps   = (bf16*)(sm + wid * 4608);      // per-wave 32 x PST
    float* Osum = (float*)(sm + 9216);           // 64 lanes x 36 floats
    float* Bsl  = (float*)(sm + 18432) + wid * 96;
    float* Ls1  = (float*)(sm + 19200);
    float* Lfin = (float*)(sm + 19328);

    const bf16* Qb = Qm + (size_t)bh * SC * DK;
    const bf16* Kb = Kf + (size_t)bh * 64 * 2048;   // 64 key-grps x (4 ks x 512)
    const bf16* Vb = Vf + (size_t)bh * 32 * 4096;   // 32 tiles x (4 ks x 2 ng x 512)
    const float* rT = relT + h * (SX + SC - 1);

    // Q B-fragments (n=q, k=dk), resident all kernel
    bf16x8 qf[4];
#pragma unroll
    for (int ks = 0; ks < 4; ks++)
        qf[ks] = *(const bf16x8*)&Qb[(size_t)(q0 + l31) * DK + ks * 16 + l5 * 8];

    f32x16 oacc[2];
#pragma unroll
    for (int ng = 0; ng < 2; ng++)
#pragma unroll
        for (int r = 0; r < 16; r++) oacc[ng][r] = 0.f;
    float lsum = 0.f;

    const float sc = 0.125f * L2E;
    const int kw0 = wid << 10;       // wave's key base

#pragma unroll 1
    for (int tt = 0; tt < 16; ++tt) {
        const int k0 = kw0 + tt * 64;
        int i0 = q0 - k0 + 1984;
        Bsl[lane] = rT[i0 + lane];
        if (lane < 31) Bsl[64 + lane] = rT[i0 + 64 + lane];

        // ---- S^T = K·Q^T per 32-key group; exp2; P->LDS ----
#pragma unroll
        for (int kg = 0; kg < 2; kg++) {
            const bf16* kb = Kb + (size_t)((k0 >> 5) + kg) * 2048 + lane * 8;
            f32x16 s;
#pragma unroll
            for (int r = 0; r < 16; r++) s[r] = 0.f;
#pragma unroll
            for (int ks = 0; ks < 4; ks++) {
                bf16x8 kf = *(const bf16x8*)(kb + ks * 512);   // contiguous 1KB wave-load
                s = MFMA32(kf, qf[ks], s);  // D[key][q], lane col = q
            }
#pragma unroll
            for (int r4 = 0; r4 < 4; r4++) {
                float p[4];
#pragma unroll
                for (int r0 = 0; r0 < 4; r0++) {
                    int n = r0 + 8 * r4 + 4 * l5;            // key_local in group
                    int ib = 63 + l31 - (kg * 32 + n);
                    p[r0] = __builtin_amdgcn_exp2f(s[r4 * 4 + r0] * sc + Bsl[ib]);
                    lsum += p[r0];
                }
                bf16x4 pk = { (bf16)p[0], (bf16)p[1], (bf16)p[2], (bf16)p[3] };
                *(bf16x4*)&Ps[l31 * PST + kg * 32 + 8 * r4 + 4 * l5] = pk;
            }
        }
        // ---- O += P @ V  (same-wave LDS RAW; no barrier) ----
        bf16x8 pf[4];
#pragma unroll
        for (int ks = 0; ks < 4; ks++)
            pf[ks] = *(const bf16x8*)&Ps[l31 * PST + ks * 16 + l5 * 8];
        const bf16* vb = Vb + (size_t)(k0 >> 6) * 4096 + lane * 8;
#pragma unroll
        for (int ng = 0; ng < 2; ng++) {
#pragma unroll
            for (int ks = 0; ks < 4; ks++) {
                bf16x8 vf = *(const bf16x8*)(vb + ng * 512 + ks * 1024);  // contiguous 1KB
                oacc[ng] = MFMA32(pf[ks], vf, oacc[ng]);  // D[q][dk], lane col = dk
            }
        }
    }

    // ---- 2-way combine (R3) ----
    lsum += __shfl_xor(lsum, 32, 64);
    if (wid == 1) {
        if (lane < 32) Ls1[l31] = lsum;
        float* Op = Osum + lane * 36;
#pragma unroll
        for (int ng = 0; ng < 2; ng++)
#pragma unroll
            for (int q = 0; q < 4; q++) {
                f32x4 v = { oacc[ng][q * 4 + 0], oacc[ng][q * 4 + 1],
                            oacc[ng][q * 4 + 2], oacc[ng][q * 4 + 3] };
                *(f32x4*)(Op + ng * 16 + q * 4) = v;
            }
    }
    __syncthreads();
    if (wid == 0) {
        lsum += Ls1[l31];
        const float* Op = Osum + lane * 36;
#pragma unroll
        for (int ng = 0; ng < 2; ng++)
#pragma unroll
            for (int q = 0; q < 4; q++) {
                f32x4 v = *(const f32x4*)(Op + ng * 16 + q * 4);
#pragma unroll
                for (int r0 = 0; r0 < 4; r0++) oacc[ng][q * 4 + r0] += v[r0];
            }
        if (lane < 32) Lfin[l31] = lsum;
        // epilogue: normalize, store bf16 [b][q][h*64+dk]
#pragma unroll
        for (int r4 = 0; r4 < 4; r4++) {
            float4 lv = *(const float4*)&Lfin[8 * r4 + 4 * l5];
            float rv[4] = { 1.f / lv.x, 1.f / lv.y, 1.f / lv.z, 1.f / lv.w };
#pragma unroll
            for (int ng = 0; ng < 2; ng++) {
#pragma unroll
                for (int r0 = 0; r0 < 4; r0++) {
                    int row = r0 + 8 * r4 + 4 * l5;
                    Oa[((size_t)(b * SX + q0 + row)) * Dm + h * 64 + ng * 32 + l31] =
                        (bf16)(oacc[ng][r4 * 4 + r0] * rv[r0]);
                }
            }
        }
    }
}

// ---------------------------------------------------------------------------
// Launch
// ---------------------------------------------------------------------------
extern "C" void kernel_launch(void* const* d_in, const int* in_sizes, int n_in,
                              void* d_out, int out_size, void* d_ws, size_t ws_size,
                              hipStream_t stream)
{
    (void)in_sizes; (void)n_in; (void)out_size; (void)ws_size;

    const float* x   = (const float*)d_in[0];
    const float* c   = (const float*)d_in[1];
    const float* Wq  = (const float*)d_in[2];
    const float* bq  = (const float*)d_in[3];
    const float* Wk  = (const float*)d_in[4];
    const float* bk  = (const float*)d_in[5];
    const float* Wv  = (const float*)d_in[6];
    const float* bv  = (const float*)d_in[7];
    const float* Wo  = (const float*)d_in[8];
    const float* bo  = (const float*)d_in[9];
    const float* rel = (const float*)d_in[10];

    char* ws = (char*)d_ws;
    // layout: Wbf 0..2MB | XCbf 2..18MB (dead after V) / Aw overlay 2..10MB
    //         Q 18..26 | Kf 26..34 | Vf 34..42 | relT 42MB+128KB
    bf16*  Wbf  = (bf16*)ws;
    bf16*  Xbf  = (bf16*)(ws + (2u << 20));
    bf16*  Cbf  = Xbf + 4194304;
    bf16*  Aw   = (bf16*)(ws + (2u << 20));      // overlays XCbf (dead by then)
    bf16*  Qw   = (bf16*)(ws + (18u << 20));
    bf16*  Kw   = (bf16*)(ws + (26u << 20));
    bf16*  Vw   = (bf16*)(ws + (34u << 20));
    float* relT = (float*)(ws + (42u << 20));

    cvt_weights<<<512, 256, 0, stream>>>(Wq, Wk, Wv, Wo, Wbf);
    cvt_xc<<<4096, 256, 0, stream>>>(x, c, Xbf);
    cvt_rel<<<dim3(16, 8), 256, 0, stream>>>(rel, relT);

    dim3 pg(4, 64);  // (N/128, M/128)
    proj_gemm<0><<<pg, 256, 0, stream>>>(Xbf, Wbf + 0 * 262144, bq, Qw);
    proj_gemm<3><<<pg, 256, 0, stream>>>(Cbf, Wbf + 1 * 262144, bk, Kw);
    proj_gemm<4><<<pg, 256, 0, stream>>>(Cbf, Wbf + 2 * 262144, bv, Vw);

    attn_kernel<<<2048, 128, 0, stream>>>(Qw, Kw, Vw, relT, Aw);

    proj_gemm<2><<<pg, 256, 0, stream>>>(Aw, Wbf + 3 * 262144, bo, d_out);
}

// Round 8
// 205.165 us; speedup vs baseline: 2.1746x; 1.0674x over previous
//
#include <hip/hip_runtime.h>
#include <hip/hip_bf16.h>
#include <cstdint>
#include <cstddef>

typedef __bf16 bf16;
typedef __bf16 bf16x4 __attribute__((ext_vector_type(4)));
typedef __bf16 bf16x8 __attribute__((ext_vector_type(8)));
typedef float f32x4 __attribute__((ext_vector_type(4)));
typedef float f32x16 __attribute__((ext_vector_type(16)));

#define MFMA16(a, b, c) __builtin_amdgcn_mfma_f32_16x16x32_bf16((a), (b), (c), 0, 0, 0)
#define MFMA32(a, b, c) __builtin_amdgcn_mfma_f32_32x32x16_bf16((a), (b), (c), 0, 0, 0)
#define GLD16(g, l) __builtin_amdgcn_global_load_lds( \
    (const __attribute__((address_space(1))) void*)(g), \
    (__attribute__((address_space(3))) void*)(l), 16, 0, 0)

constexpr int Bsz = 4, SX = 2048, SC = 2048, Dm = 512, H = 8, DK = 64;
constexpr float L2E = 1.4426950408889634f;

// ---------------------------------------------------------------------------
// cvt_all: one kernel for all conversions (block-range dispatch).
//   blocks [0,4096):    x|c fp32 -> bf16 (8 elems/thread)
//   blocks [4096,4608): weights fp32 -> bf16 packed Wq|Wk|Wv|Wo
//   blocks [4608,4736): rel_table (4095x8) -> relT (8x4095) * log2(e)
// ---------------------------------------------------------------------------
__global__ __launch_bounds__(256) void cvt_all(
    const float* __restrict__ x, const float* __restrict__ c,
    const float* __restrict__ Wq, const float* __restrict__ Wk,
    const float* __restrict__ Wv, const float* __restrict__ Wo,
    const float* __restrict__ rel,
    bf16* __restrict__ xcOut, bf16* __restrict__ wOut, float* __restrict__ relT)
{
    int blk = blockIdx.x;
    if (blk < 4096) {
        int i = (blk * 256 + threadIdx.x) * 8;
        const float* src = (i < 4194304) ? x : c;
        int off = i & 4194303;
        float4 v0 = *(const float4*)(src + off);
        float4 v1 = *(const float4*)(src + off + 4);
        bf16x8 o = { (bf16)v0.x, (bf16)v0.y, (bf16)v0.z, (bf16)v0.w,
                     (bf16)v1.x, (bf16)v1.y, (bf16)v1.z, (bf16)v1.w };
        *(bf16x8*)(xcOut + i) = o;
    } else if (blk < 4608) {
        int i = ((blk - 4096) * 256 + threadIdx.x) * 8;
        int w = i >> 18;
        int off = i & 262143;
        const float* src = (w == 0) ? Wq : (w == 1) ? Wk : (w == 2) ? Wv : Wo;
        float4 v0 = *(const float4*)(src + off);
        float4 v1 = *(const float4*)(src + off + 4);
        bf16x8 o = { (bf16)v0.x, (bf16)v0.y, (bf16)v0.z, (bf16)v0.w,
                     (bf16)v1.x, (bf16)v1.y, (bf16)v1.z, (bf16)v1.w };
        *(bf16x8*)(wOut + i) = o;
    } else {
        int q = blk - 4608;
        int h = q >> 4;
        int i = (q & 15) * 256 + threadIdx.x;
        if (i < SX + SC - 1) relT[h * (SX + SC - 1) + i] = rel[i * H + h] * L2E;
    }
}

// ---------------------------------------------------------------------------
// qkv_gemm: fused Q/K/V projections. grid (12, 64) = 768 blocks (3/CU).
// blockIdx.x: proj = x>>2 (0:Q,1:K,2:V), n0 = (x&3)*128. Tile 128x128, BK=64,
// 256 thr = 4 waves, wave tile 64x64 (4x4 MFMA16). GLD16 staging w/ per-wave
// LDS bases + XOR chunk swizzle (all correctness-proven R7).
// Epilogues (proven R5-R7):
//   Q: std [(bh)*2048 + s]*64 + dk
//   K-frag: ((((bh*64+key/32)*4+ks)*2+l5)*32+key%32)*8+j
//   V-frag: (((((bh*32+key/64)*4+ks)*2+ng)*2+l5)*32+dk%32)*8+j
// ---------------------------------------------------------------------------
__global__ __launch_bounds__(256, 3) void qkv_gemm(
    const bf16* __restrict__ Xbf, const bf16* __restrict__ Cbf,
    const bf16* __restrict__ Wbf,
    const float* __restrict__ bq, const float* __restrict__ bk,
    const float* __restrict__ bv,
    bf16* __restrict__ Qw, bf16* __restrict__ Kw, bf16* __restrict__ Vw)
{
    __shared__ alignas(16) bf16 As[128 * 64];
    __shared__ alignas(16) bf16 Bs[128 * 64];

    const int proj = blockIdx.x >> 2;
    const int n0 = (blockIdx.x & 3) * 128;
    const int m0 = blockIdx.y * 128;
    const bf16* A = (proj == 0) ? Xbf : Cbf;
    const bf16* W = Wbf + proj * 262144;
    const float* bias = (proj == 0) ? bq : (proj == 1) ? bk : bv;

    const int t = threadIdx.x;
    const int wid = t >> 6, lane = t & 63, lr = lane & 15, lq = lane >> 4;
    const int wm = (wid & 1) * 64, wn = (wid >> 1) * 64;

    const int rl = lane >> 3;             // 0..7 row within 8-row staging group
    const int ch = (lane & 7) ^ rl;       // xor-swizzled global 16B chunk

    f32x4 acc[4][4];
#pragma unroll
    for (int i = 0; i < 4; i++)
#pragma unroll
        for (int j = 0; j < 4; j++) acc[i][j] = f32x4{0.f, 0.f, 0.f, 0.f};

    for (int k0 = 0; k0 < Dm; k0 += 64) {
        const bf16* ga = A + (size_t)(m0 + wid * 32 + rl) * Dm + k0 + ch * 8;
        const bf16* gb = W + (size_t)(n0 + wid * 32 + rl) * Dm + k0 + ch * 8;
#pragma unroll
        for (int g = 0; g < 4; g++)
            GLD16(ga + (size_t)g * 8 * Dm, &As[(wid * 32 + g * 8) * 64]);
#pragma unroll
        for (int g = 0; g < 4; g++)
            GLD16(gb + (size_t)g * 8 * Dm, &Bs[(wid * 32 + g * 8) * 64]);
        __syncthreads();
#pragma unroll
        for (int ks = 0; ks < 2; ks++) {
            bf16x8 af[4], bfr[4];
#pragma unroll
            for (int mt = 0; mt < 4; mt++)
                af[mt] = *(const bf16x8*)&As[(wm + mt * 16 + lr) * 64 + (((ks * 4 + lq) ^ (lr & 7)) * 8)];
#pragma unroll
            for (int nt = 0; nt < 4; nt++)
                bfr[nt] = *(const bf16x8*)&Bs[(wn + nt * 16 + lr) * 64 + (((ks * 4 + lq) ^ (lr & 7)) * 8)];
#pragma unroll
            for (int mt = 0; mt < 4; mt++)
#pragma unroll
                for (int nt = 0; nt < 4; nt++)
                    acc[mt][nt] = MFMA16(af[mt], bfr[nt], acc[mt][nt]);
        }
        __syncthreads();
    }

    // epilogue (wave-uniform proj branch)
#pragma unroll
    for (int mt = 0; mt < 4; mt++) {
#pragma unroll
        for (int nt = 0; nt < 4; nt++) {
#pragma unroll
            for (int r = 0; r < 4; r++) {
                int m = m0 + wm + mt * 16 + lq * 4 + r;   // b*2048 + s
                int n = n0 + wn + nt * 16 + lr;           // h*64 + dk
                float v = acc[mt][nt][r] + bias[n];
                int bh = (m >> 11) * 8 + (n >> 6);
                int key = m & 2047, dk = n & 63;
                if (proj == 0) {
                    Qw[(size_t)(bh * 2048 + key) * 64 + dk] = (bf16)v;
                } else if (proj == 1) {
                    int idx = ((((bh * 64 + (key >> 5)) * 4 + (dk >> 4)) * 2 + ((dk >> 3) & 1)) * 32
                               + (key & 31)) * 8 + (dk & 7);
                    Kw[idx] = (bf16)v;
                } else {
                    int idx = (((((bh * 32 + (key >> 6)) * 4 + ((key >> 4) & 3)) * 2 + (dk >> 5)) * 2
                                + ((key >> 3) & 1)) * 32 + (dk & 31)) * 8 + (key & 7);
                    Vw[idx] = (bf16)v;
                }
            }
        }
    }
}

// ---------------------------------------------------------------------------
// out_gemm: Y = A @ Wo^T + bo, fp32 out. Tile 64(M) x 128(N), BK=64,
// grid (4, 128) = 512 blocks (2/CU). 4 waves side-by-side in N (wave 64x32).
// ---------------------------------------------------------------------------
__global__ __launch_bounds__(256, 2) void out_gemm(
    const bf16* __restrict__ A, const bf16* __restrict__ W,
    const float* __restrict__ bias, float* __restrict__ Y)
{
    __shared__ alignas(16) bf16 As[64 * 64];
    __shared__ alignas(16) bf16 Bs[128 * 64];

    const int t = threadIdx.x;
    const int n0 = blockIdx.x * 128;
    const int m0 = blockIdx.y * 64;
    const int wid = t >> 6, lane = t & 63, lr = lane & 15, lq = lane >> 4;
    const int wn = wid * 32;

    const int rl = lane >> 3;
    const int ch = (lane & 7) ^ rl;

    f32x4 acc[4][2];
#pragma unroll
    for (int i = 0; i < 4; i++)
#pragma unroll
        for (int j = 0; j < 2; j++) acc[i][j] = f32x4{0.f, 0.f, 0.f, 0.f};

    for (int k0 = 0; k0 < Dm; k0 += 64) {
        const bf16* ga = A + (size_t)(m0 + wid * 16 + rl) * Dm + k0 + ch * 8;
        const bf16* gb = W + (size_t)(n0 + wid * 32 + rl) * Dm + k0 + ch * 8;
#pragma unroll
        for (int g = 0; g < 2; g++)
            GLD16(ga + (size_t)g * 8 * Dm, &As[(wid * 16 + g * 8) * 64]);
#pragma unroll
        for (int g = 0; g < 4; g++)
            GLD16(gb + (size_t)g * 8 * Dm, &Bs[(wid * 32 + g * 8) * 64]);
        __syncthreads();
#pragma unroll
        for (int ks = 0; ks < 2; ks++) {
            bf16x8 af[4], bfr[2];
#pragma unroll
            for (int mt = 0; mt < 4; mt++)
                af[mt] = *(const bf16x8*)&As[(mt * 16 + lr) * 64 + (((ks * 4 + lq) ^ (lr & 7)) * 8)];
#pragma unroll
            for (int nt = 0; nt < 2; nt++)
                bfr[nt] = *(const bf16x8*)&Bs[(wn + nt * 16 + lr) * 64 + (((ks * 4 + lq) ^ (lr & 7)) * 8)];
#pragma unroll
            for (int mt = 0; mt < 4; mt++)
#pragma unroll
                for (int nt = 0; nt < 2; nt++)
                    acc[mt][nt] = MFMA16(af[mt], bfr[nt], acc[mt][nt]);
        }
        __syncthreads();
    }

#pragma unroll
    for (int mt = 0; mt < 4; mt++) {
#pragma unroll
        for (int nt = 0; nt < 2; nt++) {
#pragma unroll
            for (int r = 0; r < 4; r++) {
                int m = m0 + mt * 16 + lq * 4 + r;
                int n = n0 + wn + nt * 16 + lr;
                Y[(size_t)m * Dm + n] = acc[mt][nt][r] + bias[n];
            }
        }
    }
}

// ---------------------------------------------------------------------------
// attn v8 = R7 (proven: 70.4 µs, FETCH 17 MB, VGPR 64) with #pragma unroll 2
// on the tile loop: S(t+1) K-loads/MFMAs are independent of PV(t), letting the
// scheduler hoist them across the PV phase. Live-state ~96 regs < 128 cap.
// ---------------------------------------------------------------------------
constexpr int PST = 72;  // P row stride (bf16)

__global__ __launch_bounds__(128, 4) void attn_kernel(
    const bf16* __restrict__ Qm, const bf16* __restrict__ Kf,
    const bf16* __restrict__ Vf, const float* __restrict__ relT,
    bf16* __restrict__ Oa)
{
    const int id = blockIdx.x;
    const int xcd = id & 7, j = id >> 3;
    const int bh = xcd + 8 * (j & 3);
    const int q0 = (j >> 2) * 32;
    const int h = bh & 7, b = bh >> 3;
    const int t = threadIdx.x;
    const int wid = t >> 6, lane = t & 63;
    const int l31 = lane & 31, l5 = lane >> 5;

    __shared__ alignas(16) char sm[19456];
    bf16*  Ps   = (bf16*)(sm + wid * 4608);      // per-wave 32 x PST
    float* Osum = (float*)(sm + 9216);           // 64 lanes x 36 floats
    float* Bsl  = (float*)(sm + 18432) + wid * 96;
    float* Ls1  = (float*)(sm + 19200);
    float* Lfin = (float*)(sm + 19328);

    const bf16* Qb = Qm + (size_t)bh * SC * DK;
    const bf16* Kb = Kf + (size_t)bh * 64 * 2048;   // 64 key-grps x (4 ks x 512)
    const bf16* Vb = Vf + (size_t)bh * 32 * 4096;   // 32 tiles x (4 ks x 2 ng x 512)
    const float* rT = relT + h * (SX + SC - 1);

    // Q B-fragments (n=q, k=dk), resident all kernel
    bf16x8 qf[4];
#pragma unroll
    for (int ks = 0; ks < 4; ks++)
        qf[ks] = *(const bf16x8*)&Qb[(size_t)(q0 + l31) * DK + ks * 16 + l5 * 8];

    f32x16 oacc[2];
#pragma unroll
    for (int ng = 0; ng < 2; ng++)
#pragma unroll
        for (int r = 0; r < 16; r++) oacc[ng][r] = 0.f;
    float lsum = 0.f;

    const float sc = 0.125f * L2E;
    const int kw0 = wid << 10;       // wave's key base

#pragma unroll 2
    for (int tt = 0; tt < 16; ++tt) {
        const int k0 = kw0 + tt * 64;
        int i0 = q0 - k0 + 1984;
        Bsl[lane] = rT[i0 + lane];
        if (lane < 31) Bsl[64 + lane] = rT[i0 + 64 + lane];

        // ---- S^T = K·Q^T per 32-key group; exp2; P->LDS ----
#pragma unroll
        for (int kg = 0; kg < 2; kg++) {
            const bf16* kb = Kb + (size_t)((k0 >> 5) + kg) * 2048 + lane * 8;
            f32x16 s;
#pragma unroll
            for (int r = 0; r < 16; r++) s[r] = 0.f;
#pragma unroll
            for (int ks = 0; ks < 4; ks++) {
                bf16x8 kf = *(const bf16x8*)(kb + ks * 512);   // contiguous 1KB wave-load
                s = MFMA32(kf, qf[ks], s);  // D[key][q], lane col = q
            }
#pragma unroll
            for (int r4 = 0; r4 < 4; r4++) {
                float p[4];
#pragma unroll
                for (int r0 = 0; r0 < 4; r0++) {
                    int n = r0 + 8 * r4 + 4 * l5;            // key_local in group
                    int ib = 63 + l31 - (kg * 32 + n);
                    p[r0] = __builtin_amdgcn_exp2f(s[r4 * 4 + r0] * sc + Bsl[ib]);
                    lsum += p[r0];
                }
                bf16x4 pk = { (bf16)p[0], (bf16)p[1], (bf16)p[2], (bf16)p[3] };
                *(bf16x4*)&Ps[l31 * PST + kg * 32 + 8 * r4 + 4 * l5] = pk;
            }
        }
        // ---- O += P @ V  (same-wave LDS RAW; no barrier) ----
        bf16x8 pf[4];
#pragma unroll
        for (int ks = 0; ks < 4; ks++)
            pf[ks] = *(const bf16x8*)&Ps[l31 * PST + ks * 16 + l5 * 8];
        const bf16* vb = Vb + (size_t)(k0 >> 6) * 4096 + lane * 8;
#pragma unroll
        for (int ng = 0; ng < 2; ng++) {
#pragma unroll
            for (int ks = 0; ks < 4; ks++) {
                bf16x8 vf = *(const bf16x8*)(vb + ng * 512 + ks * 1024);  // contiguous 1KB
                oacc[ng] = MFMA32(pf[ks], vf, oacc[ng]);  // D[q][dk], lane col = dk
            }
        }
    }

    // ---- 2-way combine ----
    lsum += __shfl_xor(lsum, 32, 64);
    if (wid == 1) {
        if (lane < 32) Ls1[l31] = lsum;
        float* Op = Osum + lane * 36;
#pragma unroll
        for (int ng = 0; ng < 2; ng++)
#pragma unroll
            for (int q = 0; q < 4; q++) {
                f32x4 v = { oacc[ng][q * 4 + 0], oacc[ng][q * 4 + 1],
                            oacc[ng][q * 4 + 2], oacc[ng][q * 4 + 3] };
                *(f32x4*)(Op + ng * 16 + q * 4) = v;
            }
    }
    __syncthreads();
    if (wid == 0) {
        lsum += Ls1[l31];
        const float* Op = Osum + lane * 36;
#pragma unroll
        for (int ng = 0; ng < 2; ng++)
#pragma unroll
            for (int q = 0; q < 4; q++) {
                f32x4 v = *(const f32x4*)(Op + ng * 16 + q * 4);
#pragma unroll
                for (int r0 = 0; r0 < 4; r0++) oacc[ng][q * 4 + r0] += v[r0];
            }
        if (lane < 32) Lfin[l31] = lsum;
        // epilogue: normalize, store bf16 [b][q][h*64+dk]
#pragma unroll
        for (int r4 = 0; r4 < 4; r4++) {
            float4 lv = *(const float4*)&Lfin[8 * r4 + 4 * l5];
            float rv[4] = { 1.f / lv.x, 1.f / lv.y, 1.f / lv.z, 1.f / lv.w };
#pragma unroll
            for (int ng = 0; ng < 2; ng++) {
#pragma unroll
                for (int r0 = 0; r0 < 4; r0++) {
                    int row = r0 + 8 * r4 + 4 * l5;
                    Oa[((size_t)(b * SX + q0 + row)) * Dm + h * 64 + ng * 32 + l31] =
                        (bf16)(oacc[ng][r4 * 4 + r0] * rv[r0]);
                }
            }
        }
    }
}

// ---------------------------------------------------------------------------
// Launch
// ---------------------------------------------------------------------------
extern "C" void kernel_launch(void* const* d_in, const int* in_sizes, int n_in,
                              void* d_out, int out_size, void* d_ws, size_t ws_size,
                              hipStream_t stream)
{
    (void)in_sizes; (void)n_in; (void)out_size; (void)ws_size;

    const float* x   = (const float*)d_in[0];
    const float* c   = (const float*)d_in[1];
    const float* Wq  = (const float*)d_in[2];
    const float* bq  = (const float*)d_in[3];
    const float* Wk  = (const float*)d_in[4];
    const float* bk  = (const float*)d_in[5];
    const float* Wv  = (const float*)d_in[6];
    const float* bv  = (const float*)d_in[7];
    const float* Wo  = (const float*)d_in[8];
    const float* bo  = (const float*)d_in[9];
    const float* rel = (const float*)d_in[10];

    char* ws = (char*)d_ws;
    // layout: Wbf 0..2MB | XCbf 2..18MB (dead after QKV) / Aw overlay 2..10MB
    //         Q 18..26 | Kf 26..34 | Vf 34..42 | relT 42MB+128KB
    bf16*  Wbf  = (bf16*)ws;
    bf16*  Xbf  = (bf16*)(ws + (2u << 20));
    bf16*  Cbf  = Xbf + 4194304;
    bf16*  Aw   = (bf16*)(ws + (2u << 20));      // overlays XCbf (dead by then)
    bf16*  Qw   = (bf16*)(ws + (18u << 20));
    bf16*  Kw   = (bf16*)(ws + (26u << 20));
    bf16*  Vw   = (bf16*)(ws + (34u << 20));
    float* relT = (float*)(ws + (42u << 20));

    cvt_all<<<4736, 256, 0, stream>>>(x, c, Wq, Wk, Wv, Wo, rel, Xbf, Wbf, relT);

    qkv_gemm<<<dim3(12, 64), 256, 0, stream>>>(Xbf, Cbf, Wbf, bq, bk, bv, Qw, Kw, Vw);

    attn_kernel<<<2048, 128, 0, stream>>>(Qw, Kw, Vw, relT, Aw);

    out_gemm<<<dim3(4, 128), 256, 0, stream>>>(Aw, Wbf + 3 * 262144, bo, (float*)d_out);
}